// Round 11
// baseline (452.614 us; speedup 1.0000x reference)
//
#include <hip/hip_runtime.h>
#include <hip/hip_bf16.h>
#include <hip/hip_fp16.h>
#include <math.h>

#define LQ 24480

typedef short bf16x8 __attribute__((ext_vector_type(8)));   // 8 bf16 = 16B
typedef float f32x4 __attribute__((ext_vector_type(4)));
typedef float f32x4v __attribute__((ext_vector_type(4)));
typedef float f32x2 __attribute__((ext_vector_type(2)));

static __device__ __forceinline__ float bf2f(ushort u) {
    union { unsigned int i; float f; } v; v.i = ((unsigned int)u) << 16; return v.f;
}
static __device__ __forceinline__ ushort f2bf(float f) {
    __hip_bfloat16 h = __float2bfloat16(f);
    return *reinterpret_cast<ushort*>(&h);
}
static __device__ __forceinline__ float u2f_lo(unsigned int u) {
    union { unsigned int i; float f; } v; v.i = u << 16; return v.f;
}
static __device__ __forceinline__ float u2f_hi(unsigned int u) {
    union { unsigned int i; float f; } v; v.i = u & 0xffff0000u; return v.f;
}
// (lo,hi) f32 pair from packed 2xbf16
static __device__ __forceinline__ f32x2 unpk(unsigned int u) {
    union { unsigned int i; float f; } lo, hi;
    lo.i = u << 16; hi.i = u & 0xffff0000u;
    f32x2 r; r.x = lo.f; r.y = hi.f; return r;
}
// acc += v * broadcast(w.lo)  [packed dual f32 FMA]
static __device__ __forceinline__ void pk_fma_lo(f32x2& acc, f32x2 v, f32x2 w) {
    asm("v_pk_fma_f32 %0, %1, %2, %0 op_sel:[0,0,0] op_sel_hi:[1,0,1]"
        : "+v"(acc) : "v"(v), "v"(w));
}
// acc += v * broadcast(w.hi)
static __device__ __forceinline__ void pk_fma_hi(f32x2& acc, f32x2 v, f32x2 w) {
    asm("v_pk_fma_f32 %0, %1, %2, %0 op_sel:[0,1,0] op_sel_hi:[1,1,1]"
        : "+v"(acc) : "v"(v), "v"(w));
}

// ---------------------------------------------------------------------------
// Fat-tile GEMM body: block 128x128, 4 waves in 2x2, wave tile 64x64.
// Column-permuted B fragments -> each thread owns 4 consecutive cols ->
// packed 8B bf16x4 stores.
// ---------------------------------------------------------------------------
template <int RELU>
static __device__ __forceinline__ void gemm_body128(
    const ushort* __restrict__ A, const ushort* __restrict__ W,
    const float* __restrict__ bias,
    ushort* __restrict__ Cb,
    int M, int N, int K, int bm, int bn, int wave, int lane)
{
    const int wm = wave >> 1, wn = wave & 1;
    const int r = lane & 15, kblk = lane >> 4;

    f32x4 acc[4][4] = {};

    const ushort* ap[4];
    const ushort* bp[4];
#pragma unroll
    for (int i = 0; i < 4; ++i) {
        int rr = min(bm + wm * 64 + i * 16 + r, M - 1);
        ap[i] = A + (size_t)rr * K + kblk * 8;
    }
    const int c0 = bn + wn * 64 + r * 4;     // first of this thread's 4 cols
#pragma unroll
    for (int j = 0; j < 4; ++j) {
        int cc = min(c0 + j, N - 1);
        bp[j] = W + (size_t)cc * K + kblk * 8;
    }

#pragma unroll 2
    for (int k = 0; k < K; k += 32) {
        bf16x8 a[4], b[4];
#pragma unroll
        for (int i = 0; i < 4; ++i) a[i] = *(const bf16x8*)(ap[i] + k);
#pragma unroll
        for (int j = 0; j < 4; ++j) b[j] = *(const bf16x8*)(bp[j] + k);
#pragma unroll
        for (int i = 0; i < 4; ++i)
#pragma unroll
            for (int j = 0; j < 4; ++j)
                acc[i][j] = __builtin_amdgcn_mfma_f32_16x16x32_bf16(a[i], b[j], acc[i][j], 0, 0, 0);
    }

    if (c0 >= N) return;
    const float4 bv = *(const float4*)(bias + c0);
    const int orow = kblk * 4;
#pragma unroll
    for (int i = 0; i < 4; ++i)
#pragma unroll
        for (int t = 0; t < 4; ++t) {
            int rr = bm + wm * 64 + i * 16 + orow + t;
            if (rr < M) {
                float v0 = acc[i][0][t] + bv.x;
                float v1 = acc[i][1][t] + bv.y;
                float v2 = acc[i][2][t] + bv.z;
                float v3 = acc[i][3][t] + bv.w;
                if (RELU) {
                    v0 = fmaxf(v0, 0.f); v1 = fmaxf(v1, 0.f);
                    v2 = fmaxf(v2, 0.f); v3 = fmaxf(v3, 0.f);
                }
                uint2 pk;
                pk.x = (unsigned)f2bf(v0) | ((unsigned)f2bf(v1) << 16);
                pk.y = (unsigned)f2bf(v2) | ((unsigned)f2bf(v3) << 16);
                *(uint2*)(Cb + (size_t)rr * N + c0) = pk;
            }
        }
}

// Fused value-proj (2 col-blocks -> valb) + q-proj (11 col-blocks -> qout).
__global__ __launch_bounds__(256) void gemm_valq(
    const ushort* __restrict__ srcb, const ushort* __restrict__ qb,
    const ushort* __restrict__ Wv, const ushort* __restrict__ Wq,
    const float* __restrict__ b_val, const float* __restrict__ bq,
    ushort* __restrict__ valb, ushort* __restrict__ qout)
{
    const int bx = blockIdx.x;   // 0..12
    if (bx < 2) {
        gemm_body128<0>(srcb, Wv, b_val, valb, LQ, 256, 256,
                        blockIdx.y * 128, bx * 128,
                        threadIdx.x >> 6, threadIdx.x & 63);
    } else {
        gemm_body128<0>(qb, Wq, bq, qout, LQ, 1344, 256,
                        blockIdx.y * 128, (bx - 2) * 128,
                        threadIdx.x >> 6, threadIdx.x & 63);
    }
}

// ff1: relu, bf16 out
__global__ __launch_bounds__(256) void gemm_ff1(
    const ushort* __restrict__ A, const ushort* __restrict__ W,
    const float* __restrict__ bias, ushort* __restrict__ Cb)
{
    gemm_body128<1>(A, W, bias, Cb, LQ, 1024, 256,
                    blockIdx.y * 128, blockIdx.x * 128,
                    threadIdx.x >> 6, threadIdx.x & 63);
}

// ---------------------------------------------------------------------------
// Fused GEMM (N=256) + residual + LayerNorm, column-permuted epilogue:
// each thread owns 16 consecutive columns. RES16: residual is bf16.
// ---------------------------------------------------------------------------
template <int RES16, int WF32, int WBF16>
__global__ __launch_bounds__(256) void gemm_ln(
    const ushort* __restrict__ A, const ushort* __restrict__ W,
    const float* __restrict__ bias, const void* __restrict__ res,
    const float* __restrict__ g, const float* __restrict__ be,
    float* __restrict__ outF, ushort* __restrict__ outB,
    int M, int K)
{
    const int wave = threadIdx.x >> 6;
    const int lane = threadIdx.x & 63;
    const int r = lane & 15;
    const int kblk = lane >> 4;
    const int bm = blockIdx.x * 128;
    const int c0 = r * 16;                   // this thread's 16 columns

    f32x4 acc[2][16] = {};

    int row0 = bm + wave * 32 + r;
    int row1 = row0 + 16;
    row0 = min(row0, M - 1);
    row1 = min(row1, M - 1);
    const ushort* ap0 = A + (size_t)row0 * K + kblk * 8;
    const ushort* ap1 = A + (size_t)row1 * K + kblk * 8;
    const ushort* wp  = W + (size_t)c0 * K + kblk * 8;

#pragma unroll 2
    for (int k = 0; k < K; k += 32) {
        bf16x8 a0 = *(const bf16x8*)(ap0 + k);
        bf16x8 a1 = *(const bf16x8*)(ap1 + k);
#pragma unroll
        for (int ni = 0; ni < 16; ++ni) {
            bf16x8 b = *(const bf16x8*)(wp + (size_t)ni * K + k);
            acc[0][ni] = __builtin_amdgcn_mfma_f32_16x16x32_bf16(a0, b, acc[0][ni], 0, 0, 0);
            acc[1][ni] = __builtin_amdgcn_mfma_f32_16x16x32_bf16(a1, b, acc[1][ni], 0, 0, 0);
        }
    }

    const int orow = kblk * 4;

    float bv[16];
#pragma unroll
    for (int q = 0; q < 4; ++q)
        *(float4*)(bv + q * 4) = *(const float4*)(bias + c0 + q * 4);

    float mean_[2][4], rstd_[2][4];
#pragma unroll
    for (int mi = 0; mi < 2; ++mi)
#pragma unroll
        for (int j = 0; j < 4; ++j) {
            int rr = bm + wave * 32 + mi * 16 + orow + j;
            int rl = min(rr, M - 1);
            float rv[16];
            if (RES16) {
                const ushort* r16 = (const ushort*)res + (size_t)rl * 256 + c0;
                uint4 ra = *(const uint4*)r16;
                uint4 rb = *(const uint4*)(r16 + 8);
                unsigned ru[8] = {ra.x, ra.y, ra.z, ra.w, rb.x, rb.y, rb.z, rb.w};
#pragma unroll
                for (int b = 0; b < 8; ++b) {
                    rv[2 * b]     = u2f_lo(ru[b]);
                    rv[2 * b + 1] = u2f_hi(ru[b]);
                }
            } else {
                const float* rp = (const float*)res + (size_t)rl * 256 + c0;
#pragma unroll
                for (int q = 0; q < 4; ++q)
                    *(float4*)(rv + q * 4) = *(const float4*)(rp + q * 4);
            }
            float s = 0.f, s2 = 0.f;
#pragma unroll
            for (int ni = 0; ni < 16; ++ni) {
                float v = acc[mi][ni][j] + bv[ni] + rv[ni];
                acc[mi][ni][j] = v;
                s += v; s2 += v * v;
            }
#pragma unroll
            for (int off = 8; off; off >>= 1) {
                s  += __shfl_xor(s,  off, 16);
                s2 += __shfl_xor(s2, off, 16);
            }
            float mu = s * (1.f / 256.f);
            float var = s2 * (1.f / 256.f) - mu * mu;
            mean_[mi][j] = mu;
            rstd_[mi][j] = rsqrtf(var + 1e-5f);
        }

    float gv[16], bev[16];
#pragma unroll
    for (int q = 0; q < 4; ++q) {
        *(float4*)(gv + q * 4)  = *(const float4*)(g + c0 + q * 4);
        *(float4*)(bev + q * 4) = *(const float4*)(be + c0 + q * 4);
    }

#pragma unroll
    for (int mi = 0; mi < 2; ++mi)
#pragma unroll
        for (int j = 0; j < 4; ++j) {
            int rr = bm + wave * 32 + mi * 16 + orow + j;
            if (rr < M) {
                float o[16];
#pragma unroll
                for (int ni = 0; ni < 16; ++ni)
                    o[ni] = (acc[mi][ni][j] - mean_[mi][j]) * rstd_[mi][j] * gv[ni] + bev[ni];
                if (WF32) {
#pragma unroll
                    for (int q = 0; q < 4; ++q)
                        *(float4*)(outF + (size_t)rr * 256 + c0 + q * 4) = *(float4*)(o + q * 4);
                }
                if (WBF16) {
                    uint pk[8];
#pragma unroll
                    for (int b = 0; b < 8; ++b)
                        pk[b] = (unsigned)f2bf(o[2 * b]) | ((unsigned)f2bf(o[2 * b + 1]) << 16);
                    *(uint4*)(outB + (size_t)rr * 256 + c0)     = *(uint4*)pk;
                    *(uint4*)(outB + (size_t)rr * 256 + c0 + 8) = *(uint4*)(pk + 4);
                }
            }
        }
}

// ---------------------------------------------------------------------------
// src/q -> bf16 (vectorized), q = src + pos
// ---------------------------------------------------------------------------
__global__ __launch_bounds__(256) void cvt_src_q(
    const float* __restrict__ src, const float* __restrict__ pos,
    ushort* __restrict__ srcb, ushort* __restrict__ qb, int n4)
{
    int i = blockIdx.x * 256 + threadIdx.x;
    if (i >= n4) return;
    f32x4v s = *(const f32x4v*)(src + (size_t)i * 4);
    f32x4v p = *(const f32x4v*)(pos + (size_t)i * 4);
    ushort us[4], uq[4];
#pragma unroll
    for (int j = 0; j < 4; ++j) { us[j] = f2bf(s[j]); uq[j] = f2bf(s[j] + p[j]); }
    *(ulong1*)(srcb + (size_t)i * 4) = *(ulong1*)us;
    *(ulong1*)(qb   + (size_t)i * 4) = *(ulong1*)uq;
}

// weight conversions + bias concat, exact-sized 1-D grid (10 segments)
struct CvtArgs { const float* s[10]; void* d[10]; int n[10]; int isbf[10]; int bcnt[10]; };
__global__ __launch_bounds__(256) void cvt_multi(CvtArgs a)
{
    int b = blockIdx.x, seg = 0;
    while (seg < 9 && b >= a.bcnt[seg]) { b -= a.bcnt[seg]; ++seg; }
    int i = b * 256 + threadIdx.x;
    if (i >= a.n[seg]) return;
    float v = a.s[seg][i];
    if (a.isbf[seg]) ((ushort*)a.d[seg])[i] = f2bf(v);
    else             ((float*)a.d[seg])[i]  = v;
}

// ---------------------------------------------------------------------------
// Deformable attention: 4 queries/block, 4 channels/thread.
// Item record = 16B: {ushort4 corner row-idx, half4 aw-premul weights},
// laid out items[p*33 + (q*8+h)] (pad 33 -> conflict-light, immediate-
// foldable ds_read offsets in phase 2).
// ---------------------------------------------------------------------------
__global__ __launch_bounds__(256) void deform_kernel(
    const ushort* __restrict__ valb,   // [LQ,256] bf16
    const ushort* __restrict__ qout,   // [LQ,1344] bf16: samp|tsamp|logits
    const float* __restrict__ vr,      // [4,2]
    ushort* __restrict__ ob)           // [LQ,256] bf16
{
    const int q0 = blockIdx.x * 4;
    const int tid = threadIdx.x;

    __shared__ uint4 items[56 * 33];   // 29568 B

    const int lsiA[4] = {0, 18432, 23040, 24192};

    // ---- per-query geometry (q0..q0+3 share the level; starts % 4 == 0) ----
    int lqv = (q0 >= 24192) ? 3 : (q0 >= 23040) ? 2 : (q0 >= 18432) ? 1 : 0;
    int Wqv = 64 >> lqv, Hqv = 48 >> lqv;
    int slq = lsiA[lqv];
    float vrxq = vr[2 * lqv], vryq = vr[2 * lqv + 1];
    float rxb0, rxb1, rxb2, rxb3, ryb0, ryb1, ryb2, ryb3;
    int tqA0, tqA1, tqA2, tqA3;
    {
        int qi = q0 - slq;
        int iy, jx;
        iy = qi >> (6 - lqv); jx = qi & (Wqv - 1);
        tqA0 = iy / Hqv; rxb0 = ((float)jx + 0.5f) / (vrxq * (float)Wqv);
        ryb0 = ((float)iy + 0.5f) / (vryq * (float)(Hqv * 6));
        qi++; iy = qi >> (6 - lqv); jx = qi & (Wqv - 1);
        tqA1 = iy / Hqv; rxb1 = ((float)jx + 0.5f) / (vrxq * (float)Wqv);
        ryb1 = ((float)iy + 0.5f) / (vryq * (float)(Hqv * 6));
        qi++; iy = qi >> (6 - lqv); jx = qi & (Wqv - 1);
        tqA2 = iy / Hqv; rxb2 = ((float)jx + 0.5f) / (vrxq * (float)Wqv);
        ryb2 = ((float)iy + 0.5f) / (vryq * (float)(Hqv * 6));
        qi++; iy = qi >> (6 - lqv); jx = qi & (Wqv - 1);
        tqA3 = iy / Hqv; rxb3 = ((float)jx + 0.5f) / (vrxq * (float)Wqv);
        ryb3 = ((float)iy + 0.5f) / (vryq * (float)(Hqv * 6));
    }

    // ---- phase 0: softmax; group = (q,h) over 8 lanes, 7 logits/lane ----
    {
        int grp = tid >> 3;            // 0..31
        int q = grp >> 3, h = grp & 7;
        int ln = tid & 7;
        int gid = q * 8 + h;
        const ushort* lg = qout + (size_t)(q0 + q) * 1344 + 896 + h * 56;
        float lv[7];
        float m = -1e30f;
#pragma unroll
        for (int k = 0; k < 7; ++k) { lv[k] = bf2f(lg[ln + 8 * k]); m = fmaxf(m, lv[k]); }
#pragma unroll
        for (int off = 4; off; off >>= 1) m = fmaxf(m, __shfl_xor(m, off, 8));
        float s = 0.f;
#pragma unroll
        for (int k = 0; k < 7; ++k) { lv[k] = expf(lv[k] - m); s += lv[k]; }
#pragma unroll
        for (int off = 4; off; off >>= 1) s += __shfl_xor(s, off, 8);
        float inv = 1.f / s;
#pragma unroll
        for (int k = 0; k < 7; ++k)
            *(float*)&items[(ln + 8 * k) * 33 + gid] = lv[k] * inv;
    }
    __syncthreads();

    // ---- phase 1: coords for 4x448 items (7 exact iterations) ----
#pragma unroll 1
    for (int i = 0; i < 7; ++i) {
        int it = i * 256 + tid;        // 0..1791
        int q = it / 448;
        int item = it - q * 448;
        int h = item / 56;
        int p = item - h * 56;
        int l = p / 14;
        int pp = p - l * 14;
        int idx = p * 33 + q * 8 + h;

        float rx_base = (q == 0) ? rxb0 : (q == 1) ? rxb1 : (q == 2) ? rxb2 : rxb3;
        float ry_base = (q == 0) ? ryb0 : (q == 1) ? ryb1 : (q == 2) ? ryb2 : ryb3;
        int tq = (q == 0) ? tqA0 : (q == 1) ? tqA1 : (q == 2) ? tqA2 : tqA3;

        int Wl = 64 >> l;
        int Hl = 48 >> l;
        int Htl = Hl * 6;
        float vrx = vr[2 * l], vry = vr[2 * l + 1];

        float aw = *(const float*)&items[idx];

        const ushort* qrow = qout + (size_t)(q0 + q) * 1344;
        float ox, oy, ty;
        if (pp < 4) {
            ox = bf2f(qrow[h * 32 + l * 8 + pp * 2]);
            oy = bf2f(qrow[h * 32 + l * 8 + pp * 2 + 1]);
            ty = 0.f;
        } else {
            int pq = pp - 4;
            int tw = pq >> 1, nt = pq & 1;
            int tt = (tw < tq) ? tw : tw + 1;
            ty = (float)(tt - tq) * vry * (float)Hl;
            ox = bf2f(qrow[256 + h * 80 + l * 20 + tw * 4 + nt * 2]);
            oy = bf2f(qrow[256 + h * 80 + l * 20 + tw * 4 + nt * 2 + 1]);
        }
        float x = rx_base * vrx * (float)Wl - 0.5f + ox;
        float y = ry_base * vry * (float)Htl - 0.5f + ty + oy;
        float x0f = floorf(x), y0f = floorf(y);
        int x0 = (int)x0f, y0 = (int)y0f;
        float fx = x - x0f, fy = y - y0f;

        int xi0 = min(max(x0, 0), Wl - 1);
        int xi1 = min(max(x0 + 1, 0), Wl - 1);
        int yi0 = min(max(y0, 0), Htl - 1);
        int yi1 = min(max(y0 + 1, 0), Htl - 1);
        float mx0 = (x0 >= 0 && x0 < Wl) ? 1.f : 0.f;
        float mx1 = (x0 >= -1 && x0 + 1 < Wl) ? 1.f : 0.f;
        float my0 = (y0 >= 0 && y0 < Htl) ? 1.f : 0.f;
        float my1 = (y0 >= -1 && y0 + 1 < Htl) ? 1.f : 0.f;

        float gx0 = (1.f - fx) * mx0;
        float gx1 = fx * mx1;
        float gy0 = (1.f - fy) * my0 * aw;
        float gy1 = fy * my1 * aw;

        int sl = lsiA[l];
        unsigned o0 = (unsigned)(sl + yi0 * Wl + xi0);   // row index, <24480
        unsigned o1 = (unsigned)(sl + yi0 * Wl + xi1);
        unsigned o2 = (unsigned)(sl + yi1 * Wl + xi0);
        unsigned o3 = (unsigned)(sl + yi1 * Wl + xi1);

        __half2 hA = __halves2half2(__float2half(gy0 * gx0), __float2half(gy0 * gx1));
        __half2 hB = __halves2half2(__float2half(gy1 * gx0), __float2half(gy1 * gx1));

        uint4 slot;
        slot.x = o0 | (o1 << 16);
        slot.y = o2 | (o3 << 16);
        slot.z = *(const unsigned*)&hA;
        slot.w = *(const unsigned*)&hB;
        items[idx] = slot;
    }
    __syncthreads();

    // ---- phase 2: 4 channels/thread, dwordx2 gathers, packed FMA ----
    const int q = tid >> 6;            // 0..3
    const int h = (tid >> 3) & 7;
    const int c4 = tid & 7;
    const unsigned laneByte = (unsigned)(h * 64 + c4 * 8);
    const char* vbase = (const char*)valb;
    const uint4* ip = items + q * 8 + h;
    f32x2 acc01; acc01.x = 0.f; acc01.y = 0.f;
    f32x2 acc23; acc23.x = 0.f; acc23.y = 0.f;
#pragma unroll 8
    for (int p = 0; p < 56; ++p) {
        uint4 s = ip[p * 33];
        unsigned a0 = ((s.x & 0xffffu) << 9) + laneByte;
        unsigned a1 = ((s.x >> 16) << 9) + laneByte;
        unsigned a2 = ((s.y & 0xffffu) << 9) + laneByte;
        unsigned a3 = ((s.y >> 16) << 9) + laneByte;
        uint2 u0 = *(const uint2*)(vbase + (size_t)a0);
        uint2 u1 = *(const uint2*)(vbase + (size_t)a1);
        uint2 u2 = *(const uint2*)(vbase + (size_t)a2);
        uint2 u3 = *(const uint2*)(vbase + (size_t)a3);
        float2 wAf = __half22float2(*(const __half2*)&s.z);  // (w00, w10)
        float2 wBf = __half22float2(*(const __half2*)&s.w);  // (w01, w11)
        f32x2 wA; wA.x = wAf.x; wA.y = wAf.y;
        f32x2 wB; wB.x = wBf.x; wB.y = wBf.y;
        pk_fma_lo(acc01, unpk(u0.x), wA); pk_fma_lo(acc23, unpk(u0.y), wA);
        pk_fma_hi(acc01, unpk(u1.x), wA); pk_fma_hi(acc23, unpk(u1.y), wA);
        pk_fma_lo(acc01, unpk(u2.x), wB); pk_fma_lo(acc23, unpk(u2.y), wB);
        pk_fma_hi(acc01, unpk(u3.x), wB); pk_fma_hi(acc23, unpk(u3.y), wB);
    }
    uint2 packed;
    packed.x = (unsigned)f2bf(acc01.x) | ((unsigned)f2bf(acc01.y) << 16);
    packed.y = (unsigned)f2bf(acc23.x) | ((unsigned)f2bf(acc23.y) << 16);
    *(uint2*)(ob + (size_t)(q0 + q) * 256 + h * 32 + c4 * 4) = packed;
}

// ---------------------------------------------------------------------------
extern "C" void kernel_launch(void* const* d_in, const int* in_sizes, int n_in,
                              void* d_out, int out_size, void* d_ws, size_t ws_size,
                              hipStream_t stream)
{
    const float* src    = (const float*)d_in[0];
    const float* pos    = (const float*)d_in[1];
    const float* vr     = (const float*)d_in[4];
    const float* W_samp = (const float*)d_in[5];
    const float* b_samp = (const float*)d_in[6];
    const float* W_tsamp= (const float*)d_in[7];
    const float* b_tsamp= (const float*)d_in[8];
    const float* W_attn = (const float*)d_in[9];
    const float* b_attn = (const float*)d_in[10];
    const float* W_val  = (const float*)d_in[11];
    const float* b_val  = (const float*)d_in[12];
    const float* W_out  = (const float*)d_in[13];
    const float* b_out  = (const float*)d_in[14];
    const float* W_ff1  = (const float*)d_in[15];
    const float* b_ff1  = (const float*)d_in[16];
    const float* W_ff2  = (const float*)d_in[17];
    const float* b_ff2  = (const float*)d_in[18];
    const float* n1g    = (const float*)d_in[19];
    const float* n1b    = (const float*)d_in[20];
    const float* n2g    = (const float*)d_in[21];
    const float* n2b    = (const float*)d_in[22];

    // ---- workspace layout (f32 units) ----
    float* ws = (float*)d_ws;
    ushort* qout  = (ushort*)ws;                         // LQ*1344 bf16
    float* valueR = ws + (size_t)LQ * 672;               // region: LQ*256 f32
    ushort* valb  = (ushort*)valueR;                     // LQ*256 bf16
    ushort* srcb  = (ushort*)(valueR + (size_t)LQ * 256);// LQ*256 bf16
    ushort* qb    = srcb + (size_t)LQ * 256;             // LQ*256 bf16
    ushort* obuf  = qb + (size_t)LQ * 256;               // LQ*256 bf16
    float* ffB    = (float*)(obuf + (size_t)LQ * 256);   // LQ*256 f32 (spacer)
    ushort* Wq    = (ushort*)(ffB + (size_t)LQ * 256);   // 1344*256 bf16
    ushort* Wv    = Wq + 1344 * 256;
    ushort* Wo    = Wv + 256 * 256;
    ushort* Wf1   = Wo + 256 * 256;
    ushort* Wf2   = Wf1 + 1024 * 256;
    float* bq     = (float*)(Wf2 + 1024 * 256);          // 1344 f32
    // region reuse after deform:
    ushort* xB16  = (ushort*)qout;                       // LQ*256 bf16 (qout dead)
    ushort* hB16  = (ushort*)valueR;                     // LQ*1024 bf16 spans valueR..qb

    // ---- input conversions (2 launches) ----
    cvt_src_q<<<(LQ * 64 + 255) / 256, 256, 0, stream>>>(src, pos, srcb, qb, LQ * 64);
    CvtArgs ca;
    ca.s[0] = W_samp;  ca.d[0] = Wq;             ca.n[0] = 256 * 256;  ca.isbf[0] = 1;
    ca.s[1] = W_tsamp; ca.d[1] = Wq + 256 * 256; ca.n[1] = 640 * 256;  ca.isbf[1] = 1;
    ca.s[2] = W_attn;  ca.d[2] = Wq + 896 * 256; ca.n[2] = 448 * 256;  ca.isbf[2] = 1;
    ca.s[3] = W_val;   ca.d[3] = Wv;             ca.n[3] = 256 * 256;  ca.isbf[3] = 1;
    ca.s[4] = W_out;   ca.d[4] = Wo;             ca.n[4] = 256 * 256;  ca.isbf[4] = 1;
    ca.s[5] = W_ff1;   ca.d[5] = Wf1;            ca.n[5] = 1024 * 256; ca.isbf[5] = 1;
    ca.s[6] = W_ff2;   ca.d[6] = Wf2;            ca.n[6] = 256 * 1024; ca.isbf[6] = 1;
    ca.s[7] = b_samp;  ca.d[7] = bq;             ca.n[7] = 256;        ca.isbf[7] = 0;
    ca.s[8] = b_tsamp; ca.d[8] = bq + 256;       ca.n[8] = 640;        ca.isbf[8] = 0;
    ca.s[9] = b_attn;  ca.d[9] = bq + 896;       ca.n[9] = 448;        ca.isbf[9] = 0;
    int total_blocks = 0;
    for (int sgi = 0; sgi < 10; ++sgi) {
        ca.bcnt[sgi] = (ca.n[sgi] + 255) / 256;
        total_blocks += ca.bcnt[sgi];
    }
    cvt_multi<<<total_blocks, 256, 0, stream>>>(ca);

    const int GM = (LQ + 127) / 128;   // 192

    // fused: value-proj + q-proj (bf16 out), 128x128 tiles, packed stores
    gemm_valq<<<dim3(13, GM), 256, 0, stream>>>(srcb, qb, Wv, Wq, b_val, bq, valb, qout);

    // deformable attention (bf16 out), 4 queries per block
    deform_kernel<<<LQ / 4, 256, 0, stream>>>(valb, qout, vr, obuf);

    // out-proj + residual(src f32) + LN1 -> xB16 (bf16 only)
    gemm_ln<0, 0, 1><<<GM, 256, 0, stream>>>(obuf, Wo, b_out, src, n1g, n1b,
                                             nullptr, xB16, LQ, 256);

    // FFN: ff1 (relu, bf16 out) ; ff2 + residual(xB16 bf16) + LN2 -> d_out f32
    gemm_ff1<<<dim3(8, GM), 256, 0, stream>>>(xB16, Wf1, b_ff1, hB16);
    gemm_ln<1, 1, 0><<<GM, 256, 0, stream>>>(hB16, Wf2, b_ff2, xB16, n2g, n2b,
                                             (float*)d_out, nullptr, LQ, 1024);
}